// Round 6
// baseline (348.954 us; speedup 1.0000x reference)
//
#include <hip/hip_runtime.h>
#include <hip/hip_bf16.h>
#include <math.h>

typedef __attribute__((ext_vector_type(8))) short bf16x8;
typedef __attribute__((ext_vector_type(4))) float f32x4;
typedef __attribute__((ext_vector_type(4))) unsigned short u16x4;

constexpr int Bn = 64;    // dialogues
constexpr int Ln = 512;   // utterances
constexpr int Hd = 768;   // hidden
constexpr int Nn = 50;    // nodes per dialogue
constexpr int On = 768;   // output dim
constexpr int RP = 64;    // padded rows per dialogue (M = Bn*RP = 4096)

__device__ __forceinline__ f32x4 MFMA(bf16x8 a, bf16x8 b, f32x4 c) {
  return __builtin_amdgcn_mfma_f32_16x16x32_bf16(a, b, c, 0, 0, 0);
}
__device__ __forceinline__ unsigned short f2bb(float v) {
  __hip_bfloat16 h = __float2bfloat16(v);
  return *(unsigned short*)&h;
}

// ===========================================================================
// prep, one launch, job ranges by blockIdx.x:
//   [0,2304)      transpose+cvt W1,W2,Wa,Wl (f32 -> bf16^T)
//   [2304,6400)   gather+PE into padded xb (bf16) / xres (f32); pad rows = 0
//   [6400,6480)   zero the 5*Bn*RP aux accumulator region
struct PrepArgs {
  const float* src[4];
  __hip_bfloat16* dst[4];
  const float* emb;
  const int* ids;
  float* xres;
  __hip_bfloat16* xb;
  float* aux;
};

__global__ __launch_bounds__(256) void prep_kernel(PrepArgs a) {
  int bx = blockIdx.x;
  if (bx < 2304) {
    __shared__ float tile[32][33];
    int job = bx / 576, t = bx % 576;
    const float* W = a.src[job];
    __hip_bfloat16* Wt = a.dst[job];
    int tx = (t % 24) * 32, ty = (t / 24) * 32;
    int c = threadIdx.x & 31, r0 = threadIdx.x >> 5;
    for (int r = r0; r < 32; r += 8)
      tile[r][c] = W[(size_t)(tx + r) * Hd + ty + c];
    __syncthreads();
    for (int r = r0; r < 32; r += 8)
      Wt[(size_t)(ty + r) * Hd + tx + c] = __float2bfloat16(tile[c][r]);
  } else if (bx < 6400) {
    int bn = bx - 2304;          // b*RP + i
    int b = bn >> 6, i = bn & 63;
    __hip_bfloat16* xbo = a.xb + (size_t)bn * Hd;
    float* xro = a.xres + (size_t)bn * Hd;
    if (i < Nn) {
      int id = a.ids[b * Nn + i];
      const float* src = a.emb + ((size_t)b * Ln + id) * Hd;
      const float kLog = 9.210340371976184f / (float)Hd;  // ln(10000)/H
      for (int h = threadIdx.x; h < Hd; h += 256) {
        float freq = expf(-(float)(h & ~1) * kLog);
        float ang = (float)i * freq;
        float v = src[h] + ((h & 1) ? cosf(ang) : sinf(ang));
        xbo[h] = __float2bfloat16(v);
        xro[h] = v;
      }
    } else {
      for (int h = threadIdx.x; h < Hd; h += 256) {
        xbo[h] = __float2bfloat16(0.f);
        xro[h] = 0.f;
      }
    }
  } else {
    int idx = (bx - 6400) * 256 + threadIdx.x;
    if (idx < 5 * Bn * RP) a.aux[idx] = 0.f;
  }
}

// ===========================================================================
// Per-dialogue GEMM tile: C = A[b*64..+64, :] @ Wt^T + bias, 64x64 per block.
// grid = (Bn, 12). NO LDS, NO barriers: direct global->register fragment
// loads. Rationale: at this wave decomposition each A fragment is consumed
// by exactly one wave and B fragments are shared only 4-ways (L1-hit); A is
// XCD-local-L2-resident (all 12 col-blocks of dialogue b land on XCD b%8),
// Wt is L2-resident. Removing the per-K-tile __syncthreads lets the compiler
// software-pipeline the fully-unrolled K-loop (5 base ptrs + imm offsets).
// Fragments and MFMA order identical to R4/R5 -> bit-identical numerics.
// EPI 0: write Wh^T (bf16, per-dialogue [Hd][RP], packed u16x4) + fused
//        src/dst dots into o1/o2 (guarded to local row < Nn).
// EPI 1: no write; atomicAdd(o1[b*RP+row], tanh(C+bias) . avec).
template <int EPI>
__global__ __launch_bounds__(256) void gemm_kernel(
    const __hip_bfloat16* __restrict__ A, const __hip_bfloat16* __restrict__ Bt,
    const float* __restrict__ bias, __hip_bfloat16* __restrict__ WhT,
    const float* __restrict__ avec, float* __restrict__ o1,
    float* __restrict__ o2) {
  int tid = threadIdx.x;
  int wave = tid >> 6, lane = tid & 63;
  int lr = lane & 15, lq = lane >> 4;
  int b = blockIdx.x, col0 = blockIdx.y * 64;
  int row0 = b * RP;

  const __hip_bfloat16* Ap = A + (size_t)(row0 + wave * 16 + lr) * Hd + lq * 8;
  const __hip_bfloat16* Bp0 = Bt + (size_t)(col0 + 0 * 16 + lr) * Hd + lq * 8;
  const __hip_bfloat16* Bp1 = Bt + (size_t)(col0 + 1 * 16 + lr) * Hd + lq * 8;
  const __hip_bfloat16* Bp2 = Bt + (size_t)(col0 + 2 * 16 + lr) * Hd + lq * 8;
  const __hip_bfloat16* Bp3 = Bt + (size_t)(col0 + 3 * 16 + lr) * Hd + lq * 8;

  f32x4 acc[4] = {};
#pragma unroll
  for (int kt = 0; kt < Hd; kt += 64) {
    bf16x8 af0 = *(const bf16x8*)(Ap + kt);
    bf16x8 af1 = *(const bf16x8*)(Ap + kt + 32);
    acc[0] = MFMA(af0, *(const bf16x8*)(Bp0 + kt), acc[0]);
    acc[0] = MFMA(af1, *(const bf16x8*)(Bp0 + kt + 32), acc[0]);
    acc[1] = MFMA(af0, *(const bf16x8*)(Bp1 + kt), acc[1]);
    acc[1] = MFMA(af1, *(const bf16x8*)(Bp1 + kt + 32), acc[1]);
    acc[2] = MFMA(af0, *(const bf16x8*)(Bp2 + kt), acc[2]);
    acc[2] = MFMA(af1, *(const bf16x8*)(Bp2 + kt + 32), acc[2]);
    acc[3] = MFMA(af0, *(const bf16x8*)(Bp3 + kt), acc[3]);
    acc[3] = MFMA(af1, *(const bf16x8*)(Bp3 + kt + 32), acc[3]);
  }

  int lrow0 = wave * 16 + lq * 4;  // local row base (0..60, mult of 4)
  if (EPI == 0) {
    float ps[4] = {}, pd[4] = {};
#pragma unroll
    for (int ct = 0; ct < 4; ++ct) {
      int gc = col0 + ct * 16 + lr;
      float bv = bias[gc];
      float a_s = avec[gc], a_d = avec[Hd + gc];
      u16x4 pk;
#pragma unroll
      for (int r = 0; r < 4; ++r) {
        float v = acc[ct][r] + bv;
        pk[r] = f2bb(v);
        ps[r] += v * a_s;
        pd[r] += v * a_d;
      }
      *(u16x4*)(WhT + ((size_t)b * Hd + gc) * RP + lrow0) = pk;
    }
#pragma unroll
    for (int off = 8; off; off >>= 1)
#pragma unroll
      for (int r = 0; r < 4; ++r) {
        ps[r] += __shfl_xor(ps[r], off);
        pd[r] += __shfl_xor(pd[r], off);
      }
    if (lr == 0)
#pragma unroll
      for (int r = 0; r < 4; ++r) {
        int row = lrow0 + r;
        if (row < Nn) {
          atomicAdd(&o1[b * RP + row], ps[r]);
          atomicAdd(&o2[b * RP + row], pd[r]);
        }
      }
  } else {
    float pr[4] = {};
#pragma unroll
    for (int ct = 0; ct < 4; ++ct) {
      int gc = col0 + ct * 16 + lr;
      float bv = bias[gc];
      float vv_ = avec[gc];
#pragma unroll
      for (int r = 0; r < 4; ++r) pr[r] += tanhf(acc[ct][r] + bv) * vv_;
    }
#pragma unroll
    for (int off = 8; off; off >>= 1)
#pragma unroll
      for (int r = 0; r < 4; ++r) pr[r] += __shfl_xor(pr[r], off);
    if (lr == 0)
#pragma unroll
      for (int r = 0; r < 4; ++r) {
        int row = lrow0 + r;
        if (row < Nn) atomicAdd(&o1[b * RP + row], pr[r]);
      }
  }
}

// ===========================================================================
// MFMA attention apply: grid = (Bn*12), block 256 (4 waves), 64 cols/block.
// att = softmax(mask(adj, leaky_relu(ssrc_i+sdst_j+ab))) built in LDS (f32),
// converted to zero-padded bf16 A-operand; B = WhT (global).
// h[row, gc] = elu(sum_j att[row][j] WhT[gc][j]) (+xres, +hf for LAYER 2).
template <int LAYER>
__global__ __launch_bounds__(256) void attf_kernel(
    const float* __restrict__ ssrc, const float* __restrict__ sdst,
    const int* __restrict__ adj, const float* __restrict__ ab,
    const __hip_bfloat16* __restrict__ WhT, const float* __restrict__ xres,
    float* __restrict__ hf, __hip_bfloat16* __restrict__ hb) {
  int b = blockIdx.x / 12, cg = blockIdx.x % 12;
  __shared__ float attL[Nn * 52];
  __shared__ __hip_bfloat16 attB[64 * 72];
  int tid = threadIdx.x;
  float abv = ab[0];
  for (int i = tid; i < 64 * 72; i += 256) attB[i] = __float2bfloat16(0.f);
  for (int idx = tid; idx < Nn * Nn; idx += 256) {
    int i = idx / Nn, j = idx - i * Nn;
    float t = ssrc[b * RP + i] + sdst[b * RP + j] + abv;
    t = t > 0.f ? t : 0.3f * t;  // leaky_relu 0.3
    attL[i * 52 + j] = (adj[(size_t)b * Nn * Nn + idx] > 0) ? t : -9.0e15f;
  }
  __syncthreads();
  if (tid < Nn) {
    float m = -3.0e38f;
    for (int j = 0; j < Nn; ++j) m = fmaxf(m, attL[tid * 52 + j]);
    float s = 0.f;
    for (int j = 0; j < Nn; ++j) {
      float p = expf(attL[tid * 52 + j] - m);
      attL[tid * 52 + j] = p;
      s += p;
    }
    float inv = 1.f / s;
    for (int j = 0; j < Nn; ++j) attL[tid * 52 + j] *= inv;
  }
  __syncthreads();
  for (int idx = tid; idx < Nn * Nn; idx += 256) {
    int i = idx / Nn, j = idx - i * Nn;
    attB[i * 72 + j] = __float2bfloat16(attL[i * 52 + j]);
  }
  __syncthreads();

  int w = tid >> 6, lane = tid & 63, lr = lane & 15, lq = lane >> 4;
  bf16x8 a0 = *(const bf16x8*)&attB[(w * 16 + lr) * 72 + lq * 8];
  bf16x8 a1 = *(const bf16x8*)&attB[(w * 16 + lr) * 72 + 32 + lq * 8];
#pragma unroll
  for (int s = 0; s < 4; ++s) {
    int gc = cg * 64 + s * 16 + lr;
    const __hip_bfloat16* Bp = WhT + ((size_t)b * Hd + gc) * RP + lq * 8;
    f32x4 acc = {};
    acc = MFMA(a0, *(const bf16x8*)Bp, acc);
    acc = MFMA(a1, *(const bf16x8*)(Bp + 32), acc);
#pragma unroll
    for (int r = 0; r < 4; ++r) {
      float v = acc[r];
      v = v > 0.f ? v : expf(v) - 1.f;  // elu
      size_t off = ((size_t)b * RP + w * 16 + lq * 4 + r) * Hd + gc;
      if (LAYER == 2) {
        v += xres[off];
        hf[off] = v;
      }
      hb[off] = __float2bfloat16(v);
    }
  }
}

// ===========================================================================
// Pool softmax + weighted sum + final linear. grid = Bn*3: 3 blocks per
// dialogue, each computing softmax+ds redundantly (bit-identical) and one
// 256-out slice of the final linear (3x latency hiding vs 1 block/dialogue).
__global__ __launch_bounds__(256) void poolfinal_kernel(
    const float* __restrict__ sraw, const float* __restrict__ h2,
    const __hip_bfloat16* __restrict__ Wlt, const float* __restrict__ bl,
    float* __restrict__ out) {
  int b = blockIdx.x / 3, q = blockIdx.x % 3;
  __shared__ float sc[Nn];
  __shared__ float ds[Hd];
  if (threadIdx.x < 64) {
    int j = threadIdx.x;
    float e = (j < Nn) ? sraw[b * RP + j] : -3.0e38f;
    float m = e;
#pragma unroll
    for (int off = 32; off; off >>= 1) m = fmaxf(m, __shfl_xor(m, off));
    float p = (j < Nn) ? expf(e - m) : 0.f;
    float s = p;
#pragma unroll
    for (int off = 32; off; off >>= 1) s += __shfl_xor(s, off);
    if (j < Nn) sc[j] = p / s;
  }
  __syncthreads();
  for (int h = threadIdx.x; h < Hd; h += 256) {
    float a = 0.f;
#pragma unroll 10
    for (int j = 0; j < Nn; ++j) a += sc[j] * h2[((size_t)b * RP + j) * Hd + h];
    ds[h] = a;
  }
  __syncthreads();
  {
    int o = q * 256 + threadIdx.x;
    float acc = bl[o];
    const uint4* wr = (const uint4*)(Wlt + (size_t)o * Hd);
    for (int kk = 0; kk < Hd / 8; ++kk) {
      union { uint4 u; unsigned short s[8]; } w;
      w.u = wr[kk];
#pragma unroll
      for (int t = 0; t < 8; ++t)
        acc += ds[kk * 8 + t] * __uint_as_float((unsigned)w.s[t] << 16);
    }
    out[(size_t)b * On + o] = acc;
  }
}

// ===========================================================================
extern "C" void kernel_launch(void* const* d_in, const int* in_sizes, int n_in,
                              void* d_out, int out_size, void* d_ws, size_t ws_size,
                              hipStream_t stream) {
  const float* emb = (const float*)d_in[0];
  const int* ids = (const int*)d_in[1];
  const int* adj = (const int*)d_in[2];
  const float* W1 = (const float*)d_in[3];
  const float* b1 = (const float*)d_in[4];
  const float* a1 = (const float*)d_in[5];
  const float* ab1 = (const float*)d_in[6];
  const float* W2 = (const float*)d_in[7];
  const float* b2 = (const float*)d_in[8];
  const float* a2 = (const float*)d_in[9];
  const float* ab2 = (const float*)d_in[10];
  const float* Wa = (const float*)d_in[11];
  const float* ba = (const float*)d_in[12];
  const float* vv = (const float*)d_in[13];
  const float* Wl = (const float*)d_in[14];
  const float* bl = (const float*)d_in[15];
  float* out = (float*)d_out;

  char* p = (char*)d_ws;
  auto alloc = [&](size_t bytes) {
    char* r = p;
    p += (bytes + 255) & ~(size_t)255;
    return r;
  };
  __hip_bfloat16* Wt1 = (__hip_bfloat16*)alloc((size_t)Hd * Hd * 2);
  __hip_bfloat16* Wt2 = (__hip_bfloat16*)alloc((size_t)Hd * Hd * 2);
  __hip_bfloat16* Wta = (__hip_bfloat16*)alloc((size_t)Hd * Hd * 2);
  __hip_bfloat16* Wlt = (__hip_bfloat16*)alloc((size_t)Hd * On * 2);
  float* aux = (float*)alloc((size_t)5 * Bn * RP * 4);
  float* ssrc1 = aux;
  float* sdst1 = aux + Bn * RP;
  float* ssrc2 = aux + 2 * Bn * RP;
  float* sdst2 = aux + 3 * Bn * RP;
  float* sraw = aux + 4 * Bn * RP;
  __hip_bfloat16* xb = (__hip_bfloat16*)alloc((size_t)Bn * RP * Hd * 2);
  float* xres = (float*)alloc((size_t)Bn * RP * Hd * 4);
  __hip_bfloat16* WhT1 = (__hip_bfloat16*)alloc((size_t)Bn * Hd * RP * 2);
  __hip_bfloat16* WhT2 = (__hip_bfloat16*)alloc((size_t)Bn * Hd * RP * 2);
  __hip_bfloat16* h1b = (__hip_bfloat16*)alloc((size_t)Bn * RP * Hd * 2);
  __hip_bfloat16* h2b = (__hip_bfloat16*)alloc((size_t)Bn * RP * Hd * 2);
  float* h2f = (float*)alloc((size_t)Bn * RP * Hd * 4);

  PrepArgs pa;
  pa.src[0] = W1; pa.src[1] = W2; pa.src[2] = Wa; pa.src[3] = Wl;
  pa.dst[0] = Wt1; pa.dst[1] = Wt2; pa.dst[2] = Wta; pa.dst[3] = Wlt;
  pa.emb = emb; pa.ids = ids; pa.xres = xres; pa.xb = xb; pa.aux = aux;
  prep_kernel<<<6480, 256, 0, stream>>>(pa);

  dim3 ggrid(Bn, Hd / 64);   // 64 x 12
  dim3 agrid(Bn * 12);       // 768 blocks, 64 cols each
  dim3 pgrid(Bn * 3);        // 192 blocks, 256 outs each

  // --- GAT layer 1 ---
  gemm_kernel<0><<<ggrid, 256, 0, stream>>>(xb, Wt1, b1, WhT1, a1, ssrc1, sdst1);
  attf_kernel<1><<<agrid, 256, 0, stream>>>(ssrc1, sdst1, adj, ab1, WhT1,
                                            nullptr, nullptr, h1b);
  // --- GAT layer 2 (+ residual) ---
  gemm_kernel<0><<<ggrid, 256, 0, stream>>>(h1b, Wt2, b2, WhT2, a2, ssrc2, sdst2);
  attf_kernel<2><<<agrid, 256, 0, stream>>>(ssrc2, sdst2, adj, ab2, WhT2, xres,
                                            h2f, h2b);
  // --- pooling scores: sraw = tanh(h2 @ Wa + ba) . v ---
  gemm_kernel<1><<<ggrid, 256, 0, stream>>>(h2b, Wta, ba, nullptr, vv, sraw,
                                            nullptr);
  // --- pool + final linear ---
  poolfinal_kernel<<<pgrid, 256, 0, stream>>>(sraw, h2f, Wlt, bl, out);
}

// Round 8
// 260.348 us; speedup vs baseline: 1.3403x; 1.3403x over previous
//
#include <hip/hip_runtime.h>
#include <hip/hip_bf16.h>
#include <math.h>

typedef __attribute__((ext_vector_type(8))) short bf16x8;
typedef __attribute__((ext_vector_type(4))) float f32x4;
typedef __attribute__((ext_vector_type(4))) unsigned short u16x4;

constexpr int Bn = 64;    // dialogues
constexpr int Ln = 512;   // utterances
constexpr int Hd = 768;   // hidden
constexpr int Nn = 50;    // nodes per dialogue
constexpr int On = 768;   // output dim
constexpr int RP = 64;    // padded rows per dialogue (M = Bn*RP = 4096)

__device__ __forceinline__ f32x4 MFMA(bf16x8 a, bf16x8 b, f32x4 c) {
  return __builtin_amdgcn_mfma_f32_16x16x32_bf16(a, b, c, 0, 0, 0);
}
__device__ __forceinline__ unsigned short f2bb(float v) {
  __hip_bfloat16 h = __float2bfloat16(v);
  return *(unsigned short*)&h;
}
// Async global->LDS, 16B per lane. LDS dest = wave-uniform base + lane*16.
__device__ __forceinline__ void gload16(const void* g, void* l) {
  __builtin_amdgcn_global_load_lds(
      (const __attribute__((address_space(1))) void*)g,
      (__attribute__((address_space(3))) void*)l, 16, 0, 0);
}

// ===========================================================================
// prep, one launch, job ranges by blockIdx.x:
//   [0,2304)      transpose+cvt W1,W2,Wa,Wl (f32 -> bf16^T)
//   [2304,6400)   gather+PE into padded xb (bf16) / xres (f32); pad rows = 0
//   [6400,6480)   zero the 5*Bn*RP aux accumulator region
struct PrepArgs {
  const float* src[4];
  __hip_bfloat16* dst[4];
  const float* emb;
  const int* ids;
  float* xres;
  __hip_bfloat16* xb;
  float* aux;
};

__global__ __launch_bounds__(256) void prep_kernel(PrepArgs a) {
  int bx = blockIdx.x;
  if (bx < 2304) {
    __shared__ float tile[32][33];
    int job = bx / 576, t = bx % 576;
    const float* W = a.src[job];
    __hip_bfloat16* Wt = a.dst[job];
    int tx = (t % 24) * 32, ty = (t / 24) * 32;
    int c = threadIdx.x & 31, r0 = threadIdx.x >> 5;
    for (int r = r0; r < 32; r += 8)
      tile[r][c] = W[(size_t)(tx + r) * Hd + ty + c];
    __syncthreads();
    for (int r = r0; r < 32; r += 8)
      Wt[(size_t)(ty + r) * Hd + tx + c] = __float2bfloat16(tile[c][r]);
  } else if (bx < 6400) {
    int bn = bx - 2304;          // b*RP + i
    int b = bn >> 6, i = bn & 63;
    __hip_bfloat16* xbo = a.xb + (size_t)bn * Hd;
    float* xro = a.xres + (size_t)bn * Hd;
    if (i < Nn) {
      int id = a.ids[b * Nn + i];
      const float* src = a.emb + ((size_t)b * Ln + id) * Hd;
      const float kLog = 9.210340371976184f / (float)Hd;  // ln(10000)/H
      for (int h = threadIdx.x; h < Hd; h += 256) {
        float freq = expf(-(float)(h & ~1) * kLog);
        float ang = (float)i * freq;
        float v = src[h] + ((h & 1) ? cosf(ang) : sinf(ang));
        xbo[h] = __float2bfloat16(v);
        xro[h] = v;
      }
    } else {
      for (int h = threadIdx.x; h < Hd; h += 256) {
        xbo[h] = __float2bfloat16(0.f);
        xro[h] = 0.f;
      }
    }
  } else {
    int idx = (bx - 6400) * 256 + threadIdx.x;
    if (idx < 5 * Bn * RP) a.aux[idx] = 0.f;
  }
}

// ===========================================================================
// Per-dialogue GEMM tile: C = A[b*64..+64, :] @ Wt^T + bias, 64x64 per block.
// grid = (Bn, 12), block = 512 (8 waves). R5's proven gload_lds + XOR-swizzle
// staging, but each wave now owns a 16x32 sub-tile (wr=wave>>1, wc=wave&1):
// per-wave K-step work halves (6 ds_reads + 4 MFMA + 2 stage instrs), block
// critical path ~halves, residency 12 -> 24 waves/CU. Swizzle identity
// (row&7 == lr&7) holds for A rows wr*16+lr and B rows wc*32+ct*16+lr.
// Per-output MFMA order unchanged vs R4/R5 -> bit-identical numerics.
// EPI 0: write Wh^T (bf16, per-dialogue [Hd][RP], packed u16x4) + fused
//        src/dst dots into o1/o2 (guarded to local row < Nn).
// EPI 1: no write; atomicAdd(o1[b*RP+row], tanh(C+bias) . avec).
template <int EPI>
__global__ __launch_bounds__(512) void gemm_kernel(
    const __hip_bfloat16* __restrict__ A, const __hip_bfloat16* __restrict__ Bt,
    const float* __restrict__ bias, __hip_bfloat16* __restrict__ WhT,
    const float* __restrict__ avec, float* __restrict__ o1,
    float* __restrict__ o2) {
  __shared__ __hip_bfloat16 As[2][64][64];   // 8KB per buffer
  __shared__ __hip_bfloat16 Bs[2][64][64];
  int tid = threadIdx.x;
  int wave = tid >> 6, lane = tid & 63;
  int lr = lane & 15, lq = lane >> 4;
  int wr = wave >> 1, wc = wave & 1;
  int b = blockIdx.x, col0 = blockIdx.y * 64;
  int row0 = b * RP;

  // staging geometry: each wave stages 8 rows of A and 8 rows of B per
  // K-tile (1 gload16 each: 8 rows x 128B = 1KB). lane l covers row
  // (wave*8 + (l>>3)), physical chunk (l&7); source pre-swizzled.
  int srow = wave * 8 + (lane >> 3);
  int swz = ((lane & 7) ^ (lane >> 3)) * 8;  // elements within the 64-col row
  const __hip_bfloat16* Ap = A + (size_t)(row0 + srow) * Hd + swz;
  const __hip_bfloat16* Bp = Bt + (size_t)(col0 + srow) * Hd + swz;
  char* AsB = (char*)As;
  char* BsB = (char*)Bs;
  int ldsw = wave * 1024;  // wave-uniform dest base within a buffer

  auto stage = [&](int buf, int kt) {
    gload16(Ap + kt, AsB + buf * 8192 + ldsw);
    gload16(Bp + kt, BsB + buf * 8192 + ldsw);
  };

  f32x4 acc[2] = {};
  stage(0, 0);
  __syncthreads();  // drains vmcnt(0): buffer 0 ready
  int cur = 0;
  int arow = wr * 16 + lr;
  int s7 = lr & 7;             // == arow&7 == (wc*32+ct*16+lr)&7 for all ct
  int c0 = (lq ^ s7) * 16;       // physical byte offset of logical chunk lq
  int c1 = ((4 + lq) ^ s7) * 16; // ... of logical chunk 4+lq (k-half 1)
  for (int kt = 64; kt < Hd; kt += 64) {
    stage(cur ^ 1, kt);  // async into other buffer; completes by the barrier
    const char* Ab = AsB + cur * 8192 + arow * 128;
    bf16x8 af0 = *(const bf16x8*)(Ab + c0);
    bf16x8 af1 = *(const bf16x8*)(Ab + c1);
#pragma unroll
    for (int ct = 0; ct < 2; ++ct) {
      const char* Bb = BsB + cur * 8192 + (wc * 32 + ct * 16 + lr) * 128;
      acc[ct] = MFMA(af0, *(const bf16x8*)(Bb + c0), acc[ct]);
      acc[ct] = MFMA(af1, *(const bf16x8*)(Bb + c1), acc[ct]);
    }
    __syncthreads();
    cur ^= 1;
  }
  {
    const char* Ab = AsB + cur * 8192 + arow * 128;
    bf16x8 af0 = *(const bf16x8*)(Ab + c0);
    bf16x8 af1 = *(const bf16x8*)(Ab + c1);
#pragma unroll
    for (int ct = 0; ct < 2; ++ct) {
      const char* Bb = BsB + cur * 8192 + (wc * 32 + ct * 16 + lr) * 128;
      acc[ct] = MFMA(af0, *(const bf16x8*)(Bb + c0), acc[ct]);
      acc[ct] = MFMA(af1, *(const bf16x8*)(Bb + c1), acc[ct]);
    }
  }
  int lrow0 = wr * 16 + lq * 4;  // local row base (0..60, mult of 4)
  if (EPI == 0) {
    float ps[4] = {}, pd[4] = {};
#pragma unroll
    for (int ct = 0; ct < 2; ++ct) {
      int gc = col0 + wc * 32 + ct * 16 + lr;
      float bv = bias[gc];
      float a_s = avec[gc], a_d = avec[Hd + gc];
      u16x4 pk;
#pragma unroll
      for (int r = 0; r < 4; ++r) {
        float v = acc[ct][r] + bv;
        pk[r] = f2bb(v);
        ps[r] += v * a_s;
        pd[r] += v * a_d;
      }
      *(u16x4*)(WhT + ((size_t)b * Hd + gc) * RP + lrow0) = pk;
    }
#pragma unroll
    for (int off = 8; off; off >>= 1)
#pragma unroll
      for (int r = 0; r < 4; ++r) {
        ps[r] += __shfl_xor(ps[r], off);
        pd[r] += __shfl_xor(pd[r], off);
      }
    if (lr == 0)
#pragma unroll
      for (int r = 0; r < 4; ++r) {
        int row = lrow0 + r;
        if (row < Nn) {
          atomicAdd(&o1[b * RP + row], ps[r]);
          atomicAdd(&o2[b * RP + row], pd[r]);
        }
      }
  } else {
    float pr[4] = {};
#pragma unroll
    for (int ct = 0; ct < 2; ++ct) {
      int gc = col0 + wc * 32 + ct * 16 + lr;
      float bv = bias[gc];
      float vv_ = avec[gc];
#pragma unroll
      for (int r = 0; r < 4; ++r) pr[r] += tanhf(acc[ct][r] + bv) * vv_;
    }
#pragma unroll
    for (int off = 8; off; off >>= 1)
#pragma unroll
      for (int r = 0; r < 4; ++r) pr[r] += __shfl_xor(pr[r], off);
    if (lr == 0)
#pragma unroll
      for (int r = 0; r < 4; ++r) {
        int row = lrow0 + r;
        if (row < Nn) atomicAdd(&o1[b * RP + row], pr[r]);
      }
  }
}

// ===========================================================================
// MFMA attention apply: grid = (Bn*12), block 256 (4 waves), 64 cols/block.
// att = softmax(mask(adj, leaky_relu(ssrc_i+sdst_j+ab))) built in LDS (f32),
// converted to zero-padded bf16 A-operand; B = WhT (global).
// h[row, gc] = elu(sum_j att[row][j] WhT[gc][j]) (+xres, +hf for LAYER 2).
template <int LAYER>
__global__ __launch_bounds__(256) void attf_kernel(
    const float* __restrict__ ssrc, const float* __restrict__ sdst,
    const int* __restrict__ adj, const float* __restrict__ ab,
    const __hip_bfloat16* __restrict__ WhT, const float* __restrict__ xres,
    float* __restrict__ hf, __hip_bfloat16* __restrict__ hb) {
  int b = blockIdx.x / 12, cg = blockIdx.x % 12;
  __shared__ float attL[Nn * 52];
  __shared__ __hip_bfloat16 attB[64 * 72];
  int tid = threadIdx.x;
  float abv = ab[0];
  for (int i = tid; i < 64 * 72; i += 256) attB[i] = __float2bfloat16(0.f);
  for (int idx = tid; idx < Nn * Nn; idx += 256) {
    int i = idx / Nn, j = idx - i * Nn;
    float t = ssrc[b * RP + i] + sdst[b * RP + j] + abv;
    t = t > 0.f ? t : 0.3f * t;  // leaky_relu 0.3
    attL[i * 52 + j] = (adj[(size_t)b * Nn * Nn + idx] > 0) ? t : -9.0e15f;
  }
  __syncthreads();
  if (tid < Nn) {
    float m = -3.0e38f;
    for (int j = 0; j < Nn; ++j) m = fmaxf(m, attL[tid * 52 + j]);
    float s = 0.f;
    for (int j = 0; j < Nn; ++j) {
      float p = expf(attL[tid * 52 + j] - m);
      attL[tid * 52 + j] = p;
      s += p;
    }
    float inv = 1.f / s;
    for (int j = 0; j < Nn; ++j) attL[tid * 52 + j] *= inv;
  }
  __syncthreads();
  for (int idx = tid; idx < Nn * Nn; idx += 256) {
    int i = idx / Nn, j = idx - i * Nn;
    attB[i * 72 + j] = __float2bfloat16(attL[i * 52 + j]);
  }
  __syncthreads();

  int w = tid >> 6, lane = tid & 63, lr = lane & 15, lq = lane >> 4;
  bf16x8 a0 = *(const bf16x8*)&attB[(w * 16 + lr) * 72 + lq * 8];
  bf16x8 a1 = *(const bf16x8*)&attB[(w * 16 + lr) * 72 + 32 + lq * 8];
#pragma unroll
  for (int s = 0; s < 4; ++s) {
    int gc = cg * 64 + s * 16 + lr;
    const __hip_bfloat16* Bp = WhT + ((size_t)b * Hd + gc) * RP + lq * 8;
    f32x4 acc = {};
    acc = MFMA(a0, *(const bf16x8*)Bp, acc);
    acc = MFMA(a1, *(const bf16x8*)(Bp + 32), acc);
#pragma unroll
    for (int r = 0; r < 4; ++r) {
      float v = acc[r];
      v = v > 0.f ? v : expf(v) - 1.f;  // elu
      size_t off = ((size_t)b * RP + w * 16 + lq * 4 + r) * Hd + gc;
      if (LAYER == 2) {
        v += xres[off];
        hf[off] = v;
      }
      hb[off] = __float2bfloat16(v);
    }
  }
}

// ===========================================================================
// Pool softmax + weighted sum + final linear. grid = Bn*3: 3 blocks per
// dialogue, each computing softmax+ds redundantly (bit-identical) and one
// 256-out slice of the final linear (3x latency hiding vs 1 block/dialogue).
__global__ __launch_bounds__(256) void poolfinal_kernel(
    const float* __restrict__ sraw, const float* __restrict__ h2,
    const __hip_bfloat16* __restrict__ Wlt, const float* __restrict__ bl,
    float* __restrict__ out) {
  int b = blockIdx.x / 3, q = blockIdx.x % 3;
  __shared__ float sc[Nn];
  __shared__ float ds[Hd];
  if (threadIdx.x < 64) {
    int j = threadIdx.x;
    float e = (j < Nn) ? sraw[b * RP + j] : -3.0e38f;
    float m = e;
#pragma unroll
    for (int off = 32; off; off >>= 1) m = fmaxf(m, __shfl_xor(m, off));
    float p = (j < Nn) ? expf(e - m) : 0.f;
    float s = p;
#pragma unroll
    for (int off = 32; off; off >>= 1) s += __shfl_xor(s, off);
    if (j < Nn) sc[j] = p / s;
  }
  __syncthreads();
  for (int h = threadIdx.x; h < Hd; h += 256) {
    float a = 0.f;
#pragma unroll 10
    for (int j = 0; j < Nn; ++j) a += sc[j] * h2[((size_t)b * RP + j) * Hd + h];
    ds[h] = a;
  }
  __syncthreads();
  {
    int o = q * 256 + threadIdx.x;
    float acc = bl[o];
    const uint4* wr = (const uint4*)(Wlt + (size_t)o * Hd);
    for (int kk = 0; kk < Hd / 8; ++kk) {
      union { uint4 u; unsigned short s[8]; } w;
      w.u = wr[kk];
#pragma unroll
      for (int t = 0; t < 8; ++t)
        acc += ds[kk * 8 + t] * __uint_as_float((unsigned)w.s[t] << 16);
    }
    out[(size_t)b * On + o] = acc;
  }
}

// ===========================================================================
extern "C" void kernel_launch(void* const* d_in, const int* in_sizes, int n_in,
                              void* d_out, int out_size, void* d_ws, size_t ws_size,
                              hipStream_t stream) {
  const float* emb = (const float*)d_in[0];
  const int* ids = (const int*)d_in[1];
  const int* adj = (const int*)d_in[2];
  const float* W1 = (const float*)d_in[3];
  const float* b1 = (const float*)d_in[4];
  const float* a1 = (const float*)d_in[5];
  const float* ab1 = (const float*)d_in[6];
  const float* W2 = (const float*)d_in[7];
  const float* b2 = (const float*)d_in[8];
  const float* a2 = (const float*)d_in[9];
  const float* ab2 = (const float*)d_in[10];
  const float* Wa = (const float*)d_in[11];
  const float* ba = (const float*)d_in[12];
  const float* vv = (const float*)d_in[13];
  const float* Wl = (const float*)d_in[14];
  const float* bl = (const float*)d_in[15];
  float* out = (float*)d_out;

  char* p = (char*)d_ws;
  auto alloc = [&](size_t bytes) {
    char* r = p;
    p += (bytes + 255) & ~(size_t)255;
    return r;
  };
  __hip_bfloat16* Wt1 = (__hip_bfloat16*)alloc((size_t)Hd * Hd * 2);
  __hip_bfloat16* Wt2 = (__hip_bfloat16*)alloc((size_t)Hd * Hd * 2);
  __hip_bfloat16* Wta = (__hip_bfloat16*)alloc((size_t)Hd * Hd * 2);
  __hip_bfloat16* Wlt = (__hip_bfloat16*)alloc((size_t)Hd * On * 2);
  float* aux = (float*)alloc((size_t)5 * Bn * RP * 4);
  float* ssrc1 = aux;
  float* sdst1 = aux + Bn * RP;
  float* ssrc2 = aux + 2 * Bn * RP;
  float* sdst2 = aux + 3 * Bn * RP;
  float* sraw = aux + 4 * Bn * RP;
  __hip_bfloat16* xb = (__hip_bfloat16*)alloc((size_t)Bn * RP * Hd * 2);
  float* xres = (float*)alloc((size_t)Bn * RP * Hd * 4);
  __hip_bfloat16* WhT1 = (__hip_bfloat16*)alloc((size_t)Bn * Hd * RP * 2);
  __hip_bfloat16* WhT2 = (__hip_bfloat16*)alloc((size_t)Bn * Hd * RP * 2);
  __hip_bfloat16* h1b = (__hip_bfloat16*)alloc((size_t)Bn * RP * Hd * 2);
  __hip_bfloat16* h2b = (__hip_bfloat16*)alloc((size_t)Bn * RP * Hd * 2);
  float* h2f = (float*)alloc((size_t)Bn * RP * Hd * 4);

  PrepArgs pa;
  pa.src[0] = W1; pa.src[1] = W2; pa.src[2] = Wa; pa.src[3] = Wl;
  pa.dst[0] = Wt1; pa.dst[1] = Wt2; pa.dst[2] = Wta; pa.dst[3] = Wlt;
  pa.emb = emb; pa.ids = ids; pa.xres = xres; pa.xb = xb; pa.aux = aux;
  prep_kernel<<<6480, 256, 0, stream>>>(pa);

  dim3 ggrid(Bn, Hd / 64);   // 64 x 12, 512 threads (8 waves)
  dim3 agrid(Bn * 12);       // 768 blocks, 64 cols each
  dim3 pgrid(Bn * 3);        // 192 blocks, 256 outs each

  // --- GAT layer 1 ---
  gemm_kernel<0><<<ggrid, 512, 0, stream>>>(xb, Wt1, b1, WhT1, a1, ssrc1, sdst1);
  attf_kernel<1><<<agrid, 256, 0, stream>>>(ssrc1, sdst1, adj, ab1, WhT1,
                                            nullptr, nullptr, h1b);
  // --- GAT layer 2 (+ residual) ---
  gemm_kernel<0><<<ggrid, 512, 0, stream>>>(h1b, Wt2, b2, WhT2, a2, ssrc2, sdst2);
  attf_kernel<2><<<agrid, 256, 0, stream>>>(ssrc2, sdst2, adj, ab2, WhT2, xres,
                                            h2f, h2b);
  // --- pooling scores: sraw = tanh(h2 @ Wa + ba) . v ---
  gemm_kernel<1><<<ggrid, 512, 0, stream>>>(h2b, Wta, ba, nullptr, vv, sraw,
                                            nullptr);
  // --- pool + final linear ---
  poolfinal_kernel<<<pgrid, 256, 0, stream>>>(sraw, h2f, Wlt, bl, out);
}